// Round 6
// baseline (53.077 us; speedup 1.0000x reference)
//
#include <hip/hip_runtime.h>

// SumFunc: per-row softmax(d1), softmax(d2) over 10 logits, full 1-D conv -> 19 outs.
// B = 2,097,152 rows, fp32.
//
// R6 = R2 input path + R5 store path:
//   in:  flat float4 LDS staging (perfect coalescing, min request count) + cached
//        loads (inputs 168 MB stay L3-resident across replays; NT loads hurt, R4)
//   out: LDS transpose -> flat float4 NON-TEMPORAL stores (don't evict inputs, R5)
// One reused 20 KiB LDS buffer -> 8 blocks/CU (full occupancy).

constexpr int D   = 10;
constexpr int S   = 19;
constexpr int BLK = 256;
constexpr int IN_TILE  = BLK * D;   // 2560 floats per input tile
constexpr int OUT_TILE = BLK * S;   // 4864 floats
constexpr int LDS_FLOATS = (2 * IN_TILE > OUT_TILE) ? 2 * IN_TILE : OUT_TILE; // 5120

typedef float vf4 __attribute__((ext_vector_type(4)));

__global__ __launch_bounds__(BLK, 2) void sumfunc_kernel(
    const float* __restrict__ d1, const float* __restrict__ d2,
    float* __restrict__ out, int n)
{
    __shared__ float lds[LDS_FLOATS];

    const int tid = threadIdx.x;
    const long long blockStart = (long long)blockIdx.x * BLK;
    const bool full = (blockStart + BLK) <= n;

    float a[D], b[D];

    if (full) {
        // ---- coalesced float4 staging of both input tiles (640 float4 each) ----
        const float4* g1 = reinterpret_cast<const float4*>(d1 + blockStart * D);
        const float4* g2 = reinterpret_cast<const float4*>(d2 + blockStart * D);
        float4* l1 = reinterpret_cast<float4*>(lds);             // [640]
        float4* l2 = reinterpret_cast<float4*>(lds + IN_TILE);   // [640]
        l1[tid]       = g1[tid];
        l1[tid + 256] = g1[tid + 256];
        l2[tid]       = g2[tid];
        l2[tid + 256] = g2[tid + 256];
        if (tid < 128) {
            l1[tid + 512] = g1[tid + 512];
            l2[tid + 512] = g2[tid + 512];
        }
        __syncthreads();

        // ---- own row from LDS (stride-10 => <=4-way aliasing, cheap) ----
        const float2* r1 = reinterpret_cast<const float2*>(lds + tid * D);
        const float2* r2 = reinterpret_cast<const float2*>(lds + IN_TILE + tid * D);
        #pragma unroll
        for (int i = 0; i < 5; ++i) {
            float2 v1 = r1[i], v2 = r2[i];
            a[2*i] = v1.x; a[2*i+1] = v1.y;
            b[2*i] = v2.x; b[2*i+1] = v2.y;
        }
    } else if (blockStart + tid < n) {
        const float2* p1 = reinterpret_cast<const float2*>(d1 + (blockStart + tid) * D);
        const float2* p2 = reinterpret_cast<const float2*>(d2 + (blockStart + tid) * D);
        #pragma unroll
        for (int i = 0; i < 5; ++i) {
            float2 v1 = p1[i], v2 = p2[i];
            a[2*i] = v1.x; a[2*i+1] = v1.y;
            b[2*i] = v2.x; b[2*i+1] = v2.y;
        }
    } else {
        #pragma unroll
        for (int i = 0; i < D; ++i) { a[i] = 0.f; b[i] = 0.f; }
    }

    // ---- softmax numerators (stable, unnormalized) + 10x10 full conv ----
    float m1 = a[0], m2 = b[0];
    #pragma unroll
    for (int i = 1; i < D; ++i) { m1 = fmaxf(m1, a[i]); m2 = fmaxf(m2, b[i]); }
    float s1 = 0.f, s2 = 0.f;
    #pragma unroll
    for (int i = 0; i < D; ++i) {
        a[i] = __expf(a[i] - m1); s1 += a[i];
        b[i] = __expf(b[i] - m2); s2 += b[i];
    }
    const float inv = 1.0f / (s1 * s2);

    float c[S];
    #pragma unroll
    for (int k = 0; k < S; ++k) c[k] = 0.f;
    #pragma unroll
    for (int i = 0; i < D; ++i) {
        #pragma unroll
        for (int j = 0; j < D; ++j) c[i + j] = fmaf(a[i], b[j], c[i + j]);
    }

    if (full) {
        __syncthreads();   // input reads done before LDS reuse

        // stride-19 (odd) writes -> benign aliasing
        #pragma unroll
        for (int k = 0; k < S; ++k) lds[tid * S + k] = c[k] * inv;
        __syncthreads();

        // ---- flat float4 NT stores: 1216 per block ----
        const vf4* lo = reinterpret_cast<const vf4*>(lds);
        vf4* go = reinterpret_cast<vf4*>(out + blockStart * S);
        __builtin_nontemporal_store(lo[tid],       &go[tid]);
        __builtin_nontemporal_store(lo[tid + 256], &go[tid + 256]);
        __builtin_nontemporal_store(lo[tid + 512], &go[tid + 512]);
        __builtin_nontemporal_store(lo[tid + 768], &go[tid + 768]);
        if (tid < 192)
            __builtin_nontemporal_store(lo[tid + 1024], &go[tid + 1024]);
    } else if (blockStart + tid < n) {
        float* po = out + (blockStart + tid) * S;
        #pragma unroll
        for (int k = 0; k < S; ++k)
            __builtin_nontemporal_store(c[k] * inv, &po[k]);
    }
}

extern "C" void kernel_launch(void* const* d_in, const int* in_sizes, int n_in,
                              void* d_out, int out_size, void* d_ws, size_t ws_size,
                              hipStream_t stream) {
    const float* d1 = (const float*)d_in[0];
    const float* d2 = (const float*)d_in[1];
    float* out = (float*)d_out;
    const int n = in_sizes[0] / D;
    const int grid = (n + BLK - 1) / BLK;
    sumfunc_kernel<<<grid, BLK, 0, stream>>>(d1, d2, out, n);
}